// Round 9
// baseline (307.386 us; speedup 1.0000x reference)
//
#include <hip/hip_runtime.h>
#include <hip/hip_cooperative_groups.h>
#include <math.h>

namespace cg = cooperative_groups;

#define HS 4096
#define IS 2048
#define NT 4
#define NR 16384   // 4*HS
#define ZD 6144    // HS+IS

typedef float fvec4 __attribute__((ext_vector_type(4)));
typedef float ef2 __attribute__((ext_vector_type(2)));

__device__ __forceinline__ float wave_reduce(float v) {
#pragma unroll
    for (int off = 32; off > 0; off >>= 1) v += __shfl_xor(v, off, 64);
    return v;
}
__device__ __forceinline__ float sigf(float x) { return 1.0f / (1.0f + expf(-x)); }

static __device__ __forceinline__ float4 ldnt(const float4* p) {
    fvec4 v = __builtin_nontemporal_load(reinterpret_cast<const fvec4*>(p));
    return make_float4(v.x, v.y, v.z, v.w);
}

// One cooperative kernel, 256 blocks x 512 threads (proven-launchable geometry).
// Block b owns hidden units [16b,16b+16); wave w (of 8) owns units u0=16b+2w, u0+1
// (8 gate rows). weight is read from HBM exactly once: x-part in A, h-part in C
// (C also writes a fp8 copy of W_h; D,E re-read it -- same block, L2/L3-hot).
__global__ __launch_bounds__(512) void lstm_fused(
    const float* __restrict__ x,       // [4][2048]
    const int* __restrict__ target,    // [4]
    const float* __restrict__ weight,  // [16384][6144]
    const float* __restrict__ bias,    // [16384]
    const float* __restrict__ W,       // [2048][4096]
    const float* __restrict__ bvec,    // [2048]
    float* __restrict__ out,           // [1]
    unsigned int* __restrict__ Whb8,   // [16384][1024] packed fp8 (ws)
    float* __restrict__ H,             // [4][4096] (ws)
    float* __restrict__ logits)        // [4][2048] (ws)
{
    __shared__ __align__(16) float sbuf[NT * IS];  // 32 KB: x (A) / h (C..E)
    __shared__ float gxls[8][2][4][4];             // [wave][unit][gate][t]
    __shared__ float cvs[16];                      // cell state per owned unit
    __shared__ float red[512];

    const int tid = threadIdx.x;
    const int w = tid >> 6, l = tid & 63;
    const int b = blockIdx.x;
    const int u0 = b * 16 + 2 * w;
    cg::grid_group grid = cg::this_grid();

    // ---------- Phase A: stage x (32 KB) + x-dots for own 8 rows, all 4 t ----
    {
        float4* s4 = reinterpret_cast<float4*>(sbuf);
        const float4* xg = reinterpret_cast<const float4*>(x);
        for (int i = tid; i < NT * IS / 4; i += 512) s4[i] = xg[i];
    }
    __syncthreads();
    {
        const float4* xs4 = reinterpret_cast<const float4*>(sbuf);
#pragma unroll
        for (int ui = 0; ui < 2; ++ui) {
#pragma unroll
            for (int g = 0; g < 4; ++g) {
                const int row = g * HS + u0 + ui;
                const float4* xr = reinterpret_cast<const float4*>(weight + (size_t)row * ZD + HS);
                float a0 = 0.f, a1 = 0.f, a2 = 0.f, a3 = 0.f;
#pragma unroll
                for (int it = 0; it < 8; ++it) {
                    const int e = it * 64 + l;
                    const float4 wv = ldnt(&xr[e]);
                    const float4 x0 = xs4[0 * 512 + e];
                    const float4 x1 = xs4[1 * 512 + e];
                    const float4 x2 = xs4[2 * 512 + e];
                    const float4 x3 = xs4[3 * 512 + e];
                    a0 += wv.x * x0.x + wv.y * x0.y + wv.z * x0.z + wv.w * x0.w;
                    a1 += wv.x * x1.x + wv.y * x1.y + wv.z * x1.z + wv.w * x1.w;
                    a2 += wv.x * x2.x + wv.y * x2.y + wv.z * x2.z + wv.w * x2.w;
                    a3 += wv.x * x3.x + wv.y * x3.y + wv.z * x3.z + wv.w * x3.w;
                }
                a0 = wave_reduce(a0); a1 = wave_reduce(a1);
                a2 = wave_reduce(a2); a3 = wave_reduce(a3);
                if (l == 0) {
                    const float bb = bias[row];
                    gxls[w][ui][g][0] = a0 + bb;
                    gxls[w][ui][g][1] = a1 + bb;
                    gxls[w][ui][g][2] = a2 + bb;
                    gxls[w][ui][g][3] = a3 + bb;
                }
            }
        }
    }
    __syncthreads();

    // ---------- Phase B: t=0 (h0=0, c0=0) ----------
    if (l == 0) {
#pragma unroll
        for (int ui = 0; ui < 2; ++ui) {
            const int u = u0 + ui;
            const float gi = gxls[w][ui][1][0];
            const float gc = gxls[w][ui][2][0];
            const float go = gxls[w][ui][3][0];
            const float cn = tanhf(gc) * sigf(gi);
            cvs[2 * w + ui] = cn;
            H[u] = tanhf(cn) * sigf(go);
        }
    }
    grid.sync();

    // ---------- Phase C: t=1 -- fp32 W_h stream + fp8 quantize + dot ----------
    {
        float4* hb4 = reinterpret_cast<float4*>(sbuf);
        const float4* hg = reinterpret_cast<const float4*>(H);   // h1
        for (int i = tid; i < HS / 4; i += 512) hb4[i] = hg[i];
        __syncthreads();

        float acc[2][4];
#pragma unroll
        for (int ui = 0; ui < 2; ++ui) {
#pragma unroll
            for (int g = 0; g < 4; ++g) {
                const int row = g * HS + u0 + ui;
                const float4* wr = reinterpret_cast<const float4*>(weight + (size_t)row * ZD);
                unsigned int* wo = Whb8 + (size_t)row * 1024;
                float a = 0.f;
#pragma unroll
                for (int it = 0; it < 16; ++it) {
                    const int e = it * 64 + l;
                    const float4 wv = ldnt(&wr[e]);
                    const float4 h4 = hb4[e];
                    a += wv.x * h4.x + wv.y * h4.y + wv.z * h4.z + wv.w * h4.w;
                    int uq = __builtin_amdgcn_cvt_pk_fp8_f32(wv.x, wv.y, 0, false);
                    uq = __builtin_amdgcn_cvt_pk_fp8_f32(wv.z, wv.w, uq, true);
                    wo[e] = (unsigned int)uq;
                }
                acc[ui][g] = wave_reduce(a);
            }
        }
        if (l == 0) {
#pragma unroll
            for (int ui = 0; ui < 2; ++ui) {
                const int u = u0 + ui;
                const float gf = acc[ui][0] + gxls[w][ui][0][1];
                const float gi = acc[ui][1] + gxls[w][ui][1][1];
                const float gc = acc[ui][2] + gxls[w][ui][2][1];
                const float go = acc[ui][3] + gxls[w][ui][3][1];
                const float cn = cvs[2 * w + ui] * sigf(gf) + tanhf(gc) * sigf(gi);
                cvs[2 * w + ui] = cn;
                H[HS + u] = tanhf(cn) * sigf(go);
            }
        }
    }
    grid.sync();

    // ---------- Phases D,E: t=2,3 -- fp8 W_h (own rows, L2/L3-hot) ----------
    for (int t = 2; t < NT; ++t) {
        float4* hb4 = reinterpret_cast<float4*>(sbuf);
        const float4* hg = reinterpret_cast<const float4*>(H + (size_t)(t - 1) * HS);
        for (int i = tid; i < HS / 4; i += 512) hb4[i] = hg[i];
        __syncthreads();

        float acc[2][4];
#pragma unroll
        for (int ui = 0; ui < 2; ++ui) {
#pragma unroll
            for (int g = 0; g < 4; ++g) {
                const int row = g * HS + u0 + ui;
                const unsigned int* w8 = Whb8 + (size_t)row * 1024;
                float a = 0.f;
#pragma unroll
                for (int it = 0; it < 16; ++it) {
                    const int e = it * 64 + l;
                    const int uq = (int)w8[e];
                    const ef2 lo = __builtin_amdgcn_cvt_pk_f32_fp8(uq, false);
                    const ef2 hi = __builtin_amdgcn_cvt_pk_f32_fp8(uq, true);
                    const float4 h4 = hb4[e];
                    a += lo.x * h4.x + lo.y * h4.y + hi.x * h4.z + hi.y * h4.w;
                }
                acc[ui][g] = wave_reduce(a);
            }
        }
        if (l == 0) {
#pragma unroll
            for (int ui = 0; ui < 2; ++ui) {
                const int u = u0 + ui;
                const float gf = acc[ui][0] + gxls[w][ui][0][t];
                const float gi = acc[ui][1] + gxls[w][ui][1][t];
                const float gc = acc[ui][2] + gxls[w][ui][2][t];
                const float go = acc[ui][3] + gxls[w][ui][3][t];
                const float cn = cvs[2 * w + ui] * sigf(gf) + tanhf(gc) * sigf(gi);
                cvs[2 * w + ui] = cn;
                H[(size_t)t * HS + u] = tanhf(cn) * sigf(go);
            }
        }
        grid.sync();
    }

    // ---------- Phase F: logits -- one row per wave (256*8 = 2048) ----------
    {
        const int row = b * 8 + w;
        const float4* wr = reinterpret_cast<const float4*>(W + (size_t)row * HS);
        const float4* Hg = reinterpret_cast<const float4*>(H);
        float a0 = 0.f, a1 = 0.f, a2 = 0.f, a3 = 0.f;
#pragma unroll
        for (int it = 0; it < 16; ++it) {
            const int e = it * 64 + l;
            const float4 wv = ldnt(&wr[e]);
            const float4 h0 = Hg[0 * 1024 + e];
            const float4 h1 = Hg[1 * 1024 + e];
            const float4 h2 = Hg[2 * 1024 + e];
            const float4 h3 = Hg[3 * 1024 + e];
            a0 += wv.x * h0.x + wv.y * h0.y + wv.z * h0.z + wv.w * h0.w;
            a1 += wv.x * h1.x + wv.y * h1.y + wv.z * h1.z + wv.w * h1.w;
            a2 += wv.x * h2.x + wv.y * h2.y + wv.z * h2.z + wv.w * h2.w;
            a3 += wv.x * h3.x + wv.y * h3.y + wv.z * h3.z + wv.w * h3.w;
        }
        a0 = wave_reduce(a0); a1 = wave_reduce(a1);
        a2 = wave_reduce(a2); a3 = wave_reduce(a3);
        if (l == 0) {
            const float bv = bvec[row];
            logits[0 * IS + row] = a0 + bv;
            logits[1 * IS + row] = a1 + bv;
            logits[2 * IS + row] = a2 + bv;
            logits[3 * IS + row] = a3 + bv;
        }
    }
    grid.sync();

    // ---------- Phase G: loss (block 0) ----------
    if (b == 0) {
        float total = 0.f;
        for (int t = 0; t < NT; ++t) {
            const float* row = logits + (size_t)t * IS;
            float m = -1e30f;
            for (int r = tid; r < IS; r += 512) m = fmaxf(m, row[r]);
            red[tid] = m;
            __syncthreads();
            for (int s = 256; s > 0; s >>= 1) {
                if (tid < s) red[tid] = fmaxf(red[tid], red[tid + s]);
                __syncthreads();
            }
            m = red[0];
            __syncthreads();
            float sum = 0.f;
            for (int r = tid; r < IS; r += 512) sum += expf(row[r] - m);
            red[tid] = sum;
            __syncthreads();
            for (int s = 256; s > 0; s >>= 1) {
                if (tid < s) red[tid] += red[tid + s];
                __syncthreads();
            }
            if (tid == 0) total += (m + logf(red[0])) - row[target[t]];
            __syncthreads();
        }
        if (tid == 0) out[0] = total;
    }
}

extern "C" void kernel_launch(void* const* d_in, const int* in_sizes, int n_in,
                              void* d_out, int out_size, void* d_ws, size_t ws_size,
                              hipStream_t stream) {
    const float* x      = (const float*)d_in[0];   // [4][1][2048]
    const int*   target = (const int*)  d_in[1];   // [4][1]
    const float* weight = (const float*)d_in[2];   // [16384][6144]
    const float* bias   = (const float*)d_in[3];   // [16384]
    const float* W      = (const float*)d_in[4];   // [2048][4096]
    const float* bvec   = (const float*)d_in[5];   // [2048]
    float* out = (float*)d_out;

    // workspace: fp8 W_h copy (64 MB), then fp32 scratch
    unsigned int* Whb8 = (unsigned int*)d_ws;                    // 16384*1024 dwords
    float* fws = (float*)((char*)d_ws + (size_t)NR * 1024 * 4);
    float* H      = fws;                                         // 4*4096
    float* logits = fws + NT * HS;                               // 4*2048

    void* args[] = {(void*)&x, (void*)&target, (void*)&weight, (void*)&bias,
                    (void*)&W, (void*)&bvec, (void*)&out, (void*)&Whb8,
                    (void*)&H, (void*)&logits};
    (void)hipLaunchCooperativeKernel((void*)lstm_fused, dim3(256), dim3(512), args, 0, stream);
}